// Round 11
// baseline (337.222 us; speedup 1.0000x reference)
//
#include <hip/hip_runtime.h>

typedef short short8 __attribute__((ext_vector_type(8)));
typedef float f32x16 __attribute__((ext_vector_type(16)));
typedef unsigned short ushort8_t __attribute__((ext_vector_type(8)));

#define O_CH 128
#define I_CH 128
#define HW 112
#define PLANE (HW * HW)        // 12544
#define NCOLR 114              // real staged cols (112 + 2 halo)
#define NCOL2 130              // allocated cols (cols 114..129 = never-written pad)
#define BUFB (3 * NCOL2 * 64)  // bytes per LDS buffer = 24960

__device__ __forceinline__ unsigned short f2bf(float f) {
  union { float f; unsigned u; } v; v.f = f;
  unsigned r = v.u + 0x7FFFu + ((v.u >> 16) & 1u);   // RNE (weights only)
  return (unsigned short)(r >> 16);
}

// one-instruction truncate-pack: [lo,hi] floats -> packed bf16 pair
__device__ __forceinline__ unsigned pktrunc(float lo, float hi) {
  union { float f; unsigned u; } a, b; a.f = lo; b.f = hi;
  return __builtin_amdgcn_perm(b.u, a.u, 0x07060302u);
}

__global__ void wsynth_kernel(const float* __restrict__ core,
                              const float* __restrict__ periph,
                              const float* __restrict__ thr,
                              const float* __restrict__ scale,
                              unsigned short* __restrict__ Wb) {
  int idx = blockIdx.x * blockDim.x + threadIdx.x;   // o*128 + i
  if (idx >= O_CH * I_CH) return;
  int o = idx >> 7;
  float c = core[idx];
  float s = scale[0];
  float g = 1.0f / (1.0f + __expf(-s * (fabsf(c) - thr[o])));
#pragma unroll
  for (int tap = 0; tap < 9; ++tap) {
    float p  = (tap == 4) ? 1.0f : periph[tap < 4 ? tap : tap - 1];
    float gg = (tap == 4) ? 1.0f : g;
    Wb[tap * (O_CH * I_CH) + idx] = f2bf(c * p * gg);   // layout [tap][o][i]
  }
}

__global__ __launch_bounds__(256, 3)
void conv_kernel(const float* __restrict__ X,
                 const unsigned short* __restrict__ Wb,
                 float* __restrict__ Out) {
  // 2 buffers x [row 0..2][col 0..129][32 ch] bf16; col-row = 64 B = 4 slots of 16 B.
  // Write swizzle (R9-verified): slot' = chgrp ^ ((col>>1)&3).
  __shared__ unsigned short Xs[2 * 3 * NCOL2 * 32];   // 49,920 B -> 3 WGs/CU
  char* lds = (char*)Xs;

  // XCD-chunked swizzle: 3584 = 8 XCDs x 448 (R6-verified)
  const int bid = blockIdx.x;
  const int L = (bid & 7) * 448 + (bid >> 3);
  const int b = L / HW;
  const int y = L - b * HW;

  const int t    = threadIdx.x;
  const int wv   = t >> 6;             // wave 0..3
  const int l    = t & 63;
  const int ln32 = l & 31;             // 32x32 frag lane (col / o-row)
  const int hi2  = l >> 5;             // k-half-of-8 selector
  const int mi   = wv >> 1;            // o-half: o in [mi*64, +64)
  const int ci   = wv & 1;             // col-half: cols [ci*64, +64)

  // staging coords (R9-identical)
  const int c    = t & 127;            // staged col (input col + 1)
  const int chb  = (t >> 7) * 16;      // local channel base: 0 or 16
  const int icol = c - 1;
  const bool cok = (c < NCOLR);
  const int wxor = (c >> 1) & 3;       // verified conflict-free write swizzle

  f32x16 acc[2][2];                    // [mt][cf]
#pragma unroll
  for (int mt = 0; mt < 2; ++mt)
#pragma unroll
    for (int cf = 0; cf < 2; ++cf)
      acc[mt][cf] = (f32x16)0.0f;

#define LOAD16(V, KCH, SUB)                                                     \
  {                                                                             \
    const int row_ = y + (SUB)-1;                                               \
    const bool ok_ = (row_ >= 0) && (row_ < HW) && (icol >= 0) && (icol < HW);  \
    const float* sp_ = X + ((size_t)(b * I_CH + (KCH) + chb) * HW + row_) * HW  \
                       + icol;                                                  \
    _Pragma("unroll") for (int j = 0; j < 16; ++j) V[j] = 0.0f;                 \
    if (ok_) {                                                                  \
      _Pragma("unroll") for (int j = 0; j < 16; ++j) V[j] = sp_[j * PLANE];     \
    }                                                                           \
  }

#define WRITE16(V, SUB, WB)                                                     \
  if (cok) {                                                                    \
    const int base_ = ((SUB)*NCOL2 + c) * 64;                                   \
    _Pragma("unroll") for (int q = 0; q < 2; ++q) {                             \
      union { ushort8_t s; unsigned u[4]; } pk_;                                \
      pk_.u[0] = pktrunc(V[q * 8 + 0], V[q * 8 + 1]);                           \
      pk_.u[1] = pktrunc(V[q * 8 + 2], V[q * 8 + 3]);                           \
      pk_.u[2] = pktrunc(V[q * 8 + 4], V[q * 8 + 5]);                           \
      pk_.u[3] = pktrunc(V[q * 8 + 6], V[q * 8 + 7]);                           \
      const int slot_ = ((chb >> 3) + q) ^ wxor;                                \
      *reinterpret_cast<ushort8_t*>((WB) + base_ + slot_ * 16) = pk_.s;         \
    }                                                                           \
  }

  // A-fragments for one sub-phase: [dx][mt][ksub]; issued BEFORE staging loads
  // so the pre-MFMA vmcnt wait does not entangle with the staging queue (R10 lesson).
#define APLOAD32(AF, SUB, K)                                                    \
  _Pragma("unroll") for (int dx = 0; dx < 3; ++dx)                              \
    _Pragma("unroll") for (int mt = 0; mt < 2; ++mt)                            \
      _Pragma("unroll") for (int ks = 0; ks < 2; ++ks)                          \
        AF[dx][mt][ks] = *reinterpret_cast<const short8*>(                      \
            Wb + ((SUB)*3 + dx) * (O_CH * I_CH)                                 \
               + (mi * 64 + mt * 32 + ln32) * I_CH + (K)*32 + ks * 16 + hi2 * 8);

  // compute sub-phase: 12 b128 B-reads, 24 MFMAs (each B-read feeds 2 MFMAs)
#define COMPUTE_SUB32(SUB, RB, AF)                                              \
  _Pragma("unroll") for (int dx = 0; dx < 3; ++dx) {                            \
    _Pragma("unroll") for (int cf = 0; cf < 2; ++cf) {                          \
      const int s_ = ci * 64 + cf * 32 + dx + ln32;                             \
      _Pragma("unroll") for (int ks = 0; ks < 2; ++ks) {                        \
        const int slot_ = (ks * 2 + hi2) ^ ((s_ >> 1) & 3);                     \
        short8 bb_ = *reinterpret_cast<const short8*>(                          \
            (RB) + ((SUB)*NCOL2 + s_) * 64 + slot_ * 16);                       \
        acc[0][cf] = __builtin_amdgcn_mfma_f32_32x32x16_bf16(AF[dx][0][ks], bb_, acc[0][cf], 0, 0, 0); \
        acc[1][cf] = __builtin_amdgcn_mfma_f32_32x32x16_bf16(AF[dx][1][ks], bb_, acc[1][cf], 0, 0, 0); \
      }                                                                         \
    }                                                                           \
  }

  // ---- prologue: stage chunk 0 into buffer 0 ----
  {
    float P0[16], P1[16], P2[16];
    LOAD16(P0, 0, 0)
    LOAD16(P1, 0, 1)
    LOAD16(P2, 0, 2)
    WRITE16(P0, 0, lds)
    WRITE16(P1, 1, lds)
    WRITE16(P2, 2, lds)
  }
  __syncthreads();

  // ---- main loop: 4 chunks of 32 ch, double-buffered, lag-1 writes (R9 skeleton) ----
#pragma unroll
  for (int k = 0; k < 4; ++k) {
    char* rbuf = lds + (k & 1) * BUFB;
    char* wbuf = lds + ((k & 1) ^ 1) * BUFB;
    float LA[16], LB[16];
    short8 AF[3][2][2];

    // sub 0: A-loads first, then stage-load (k+1,0); compute sub0
    APLOAD32(AF, 0, k)
    if (k < 3) LOAD16(LA, (k + 1) * 32, 0)
    COMPUTE_SUB32(0, rbuf, AF)

    // sub 1: A-loads; stage-load (k+1,1); compute sub1; write sub0 (lag-1)
    APLOAD32(AF, 1, k)
    if (k < 3) LOAD16(LB, (k + 1) * 32, 1)
    COMPUTE_SUB32(1, rbuf, AF)
    if (k < 3) WRITE16(LA, 0, wbuf)

    // sub 2: A-loads; stage-load (k+1,2); compute sub2; write sub1, sub2
    APLOAD32(AF, 2, k)
    if (k < 3) LOAD16(LA, (k + 1) * 32, 2)
    COMPUTE_SUB32(2, rbuf, AF)
    if (k < 3) {
      WRITE16(LB, 1, wbuf)
      WRITE16(LA, 2, wbuf)
      __syncthreads();
    }
  }

  // ---- epilogue: 32x32 C/D map col=lane&31, row=(reg&3)+8*(reg>>2)+4*(lane>>5) ----
#pragma unroll
  for (int mt = 0; mt < 2; ++mt) {
#pragma unroll
    for (int cf = 0; cf < 2; ++cf) {
      const int colb = ci * 64 + cf * 32 + ln32;
      if (colb < HW) {
        float* po = Out + (size_t)b * O_CH * PLANE + (size_t)y * HW + colb
                  + (size_t)(mi * 64 + mt * 32) * PLANE;
#pragma unroll
        for (int reg = 0; reg < 16; ++reg) {
          const int row = (reg & 3) + 8 * (reg >> 2) + 4 * hi2;
          po[(size_t)row * PLANE] = acc[mt][cf][reg];
        }
      }
    }
  }
}

extern "C" void kernel_launch(void* const* d_in, const int* in_sizes, int n_in,
                              void* d_out, int out_size, void* d_ws, size_t ws_size,
                              hipStream_t stream) {
  const float* x      = (const float*)d_in[0];
  const float* core   = (const float*)d_in[1];
  const float* periph = (const float*)d_in[2];
  const float* thr    = (const float*)d_in[3];
  const float* scale  = (const float*)d_in[4];
  unsigned short* Wb  = (unsigned short*)d_ws;   // 9*128*128*2 = 294,912 B

  wsynth_kernel<<<(O_CH * I_CH + 255) / 256, 256, 0, stream>>>(core, periph, thr, scale, Wb);

  const int grid = 32 * HW;   // one WG per (batch, output row) = 3584
  conv_kernel<<<grid, 256, 0, stream>>>(x, Wb, (float*)d_out);
}